// Round 6
// baseline (37203.113 us; speedup 1.0000x reference)
//
#include <hip/hip_runtime.h>

#define VD 128
#define HD 1024
#define BD 64
#define TD 256
#define NB 256  // persistent grid: 1 block/CU

typedef __bf16 bf16;
typedef __bf16 bf16x8 __attribute__((ext_vector_type(8)));
typedef __bf16 bf16x4 __attribute__((ext_vector_type(4)));
typedef float f32x4 __attribute__((ext_vector_type(4)));

// ---- ws layout (byte offsets) ----
#define OFF_OUTS 0ull                           // bf16 [T][B][H]   33,554,432 B
#define OFF_XW   33554432ull                    // bf16 [T][B][V]    4,194,304 B
#define OFF_WA1  (OFF_XW  + 4194304ull)         // bf16 [4H][V]      1,048,576 B
#define OFF_WA2  (OFF_WA1 + 1048576ull)         // bf16 [4H][H]      8,388,608 B
#define OFF_WB1  (OFF_WA2 + 8388608ull)         // bf16 [4H][H]
#define OFF_WB2  (OFF_WB1 + 8388608ull)         // bf16 [4H][H]
#define OFF_WFC  (OFF_WB2 + 8388608ull)         // bf16 [V][H]         262,144 B
#define OFF_BUFA (OFF_WFC + 262144ull)          // bf16 [2][B][H]      262,144 B
#define OFF_BUFB (OFF_BUFA + 262144ull)
#define OFF_CAF  (OFF_BUFB + 262144ull)         // fp32 [B][H]
#define OFF_CBF  (OFF_CAF + 262144ull)
#define OFF_BAR  (OFF_CBF + 262144ull)          // int[2]

struct Params {
  const bf16 *x, *WA1, *WA2, *WB1, *WB2;  // bf16 canonical (ws)
  const float *bA1, *bA2, *bB1, *bB2;     // fp32 biases (inputs)
  bf16 *bufA, *bufB, *outs;
  float *cA, *cB;
  int *bar;
};

__device__ __forceinline__ bf16x8 ld8(const bf16* p) {
  return *reinterpret_cast<const bf16x8*>(p);
}
__device__ __forceinline__ float sigf(float x) { return 1.f / (1.f + __expf(-x)); }

// Cross-XCD sense barrier — functionally PROVEN in R2 (bit-identical output to
// stream-ordered launches). Monotonic target avoids ABA; fences for G16.
__device__ __forceinline__ void grid_barrier(int* bar, int target) {
  __threadfence();
  __syncthreads();
  if (threadIdx.x == 0) {
    if (__hip_atomic_fetch_add(&bar[0], 1, __ATOMIC_ACQ_REL, __HIP_MEMORY_SCOPE_AGENT) == NB - 1) {
      __hip_atomic_store(&bar[0], 0, __ATOMIC_RELAXED, __HIP_MEMORY_SCOPE_AGENT);
      __hip_atomic_fetch_add(&bar[1], 1, __ATOMIC_ACQ_REL, __HIP_MEMORY_SCOPE_AGENT);
    } else {
      while (__hip_atomic_load(&bar[1], __ATOMIC_ACQUIRE, __HIP_MEMORY_SCOPE_AGENT) < target) {
        __builtin_amdgcn_s_sleep(1);
      }
    }
  }
  __syncthreads();
  __threadfence();
}

// fp32 -> bf16 staging: x, WA1, WA2, WB1, WB2, Wfc. 4 elems/thread via float4.
__global__ void conv_k(const float* x, const float* WA1, const float* WA2,
                       const float* WB1, const float* WB2, const float* Wfc,
                       char* ws) {
  const size_t g4 = (size_t)blockIdx.x * 256 + threadIdx.x;
  size_t i = g4 * 4;
  const float* src;
  bf16* dst;
  size_t off;
  if (i < 2097152ull)        { src = x;   dst = (bf16*)(ws + OFF_XW);  off = i; }
  else if (i < 2621440ull)   { src = WA1; dst = (bf16*)(ws + OFF_WA1); off = i - 2097152ull; }
  else if (i < 6815744ull)   { src = WA2; dst = (bf16*)(ws + OFF_WA2); off = i - 2621440ull; }
  else if (i < 11010048ull)  { src = WB1; dst = (bf16*)(ws + OFF_WB1); off = i - 6815744ull; }
  else if (i < 15204352ull)  { src = WB2; dst = (bf16*)(ws + OFF_WB2); off = i - 11010048ull; }
  else if (i < 15335424ull)  { src = Wfc; dst = (bf16*)(ws + OFF_WFC); off = i - 15204352ull; }
  else return;
  float4 v = *reinterpret_cast<const float4*>(src + off);
  bf16x4 o = { (bf16)v.x, (bf16)v.y, (bf16)v.z, (bf16)v.w };
  *reinterpret_cast<bf16x4*>(dst + off) = o;
}

__global__ void init_k(const float* hA, const float* cA, const float* hB, const float* cB,
                       char* ws) {
  int i = blockIdx.x * 256 + threadIdx.x;  // 65536 = B*H
  ((bf16*)(ws + OFF_BUFA))[i] = (bf16)hA[i];
  ((bf16*)(ws + OFF_BUFB))[i] = (bf16)hB[i];
  ((float*)(ws + OFF_CAF))[i] = cA[i];
  ((float*)(ws + OFF_CBF))[i] = cB[i];
  if (i == 0) { ((int*)(ws + OFF_BAR))[0] = 0; ((int*)(ws + OFF_BAR))[1] = 0; }
}

// Persistent fused 2-layer LSTM: 257 phases, grid barrier between phases.
// Phase t: A-step t (t<T) + B-step t-1 (t>=1). Block bk owns h-columns
// j0..j0+3 of BOTH cells. Waves: wv>>2 = cell, wv&3 = K-quarter.
// mfma_f32_16x16x32_bf16 -> LDS partials -> 512-thread elementwise update.
__global__ void __launch_bounds__(512) lstm_k(Params p) {
  __shared__ float part[8][16][65];
  const int tid = threadIdx.x;
  const int wv = tid >> 6, lane = tid & 63;
  const int lrow = lane & 15, q = lane >> 4;
  const int j0 = blockIdx.x * 4;
  const int cs = wv >> 2, kq = wv & 3;
  const int gate = lrow >> 2, jj = lrow & 3;
  const int grow = gate * HD + j0 + jj;

  const bf16 *w1, *w2;
  if (cs == 0) { w1 = p.WA1 + grow * VD + q * 8; w2 = p.WA2 + (size_t)grow * HD + q * 8; }
  else         { w1 = p.WB1 + (size_t)grow * HD + q * 8; w2 = p.WB2 + (size_t)grow * HD + q * 8; }

  // elementwise role: tid 0..255 -> cell A, 256..511 -> cell B; (batch, jj)
  const int eb = tid & 63;
  const int ejj = (tid >> 6) & 3;
  const int ecs = tid >> 8;
  const int ej = j0 + ejj;
  const int eidx = eb * HD + ej;
  float ebias[4];
  {
    const float* b1 = ecs ? p.bB1 : p.bA1;
    const float* b2 = ecs ? p.bB2 : p.bA2;
#pragma unroll
    for (int g = 0; g < 4; g++) ebias[g] = b1[g * HD + ej] + b2[g * HD + ej];
  }
  float* ec = ecs ? p.cB : p.cA;

#pragma unroll 1
  for (int t = 0; t <= TD; t++) {
    const bool active = (cs == 0) ? (t < TD) : (t >= 1);
    const bf16* hA = p.bufA + ((t & 1) ? (size_t)BD * HD : 0);
    if (active) {
      f32x4 acc[4] = {};
      if (cs == 0) {
        // K-chain 1152 = x(128) + hA(1024); quarter kq = [kq*288, kq*288+288)
        if (kq == 0) {
          const bf16* xb = p.x + (size_t)t * BD * VD + q * 8;
#pragma unroll
          for (int s = 0; s < 4; s++) {
            bf16x8 bfv = ld8(w1 + s * 32);
            const bf16* ap = xb + s * 32;
#pragma unroll
            for (int m = 0; m < 4; m++) {
              bf16x8 afv = ld8(ap + (m * 16 + lrow) * VD);
              acc[m] = __builtin_amdgcn_mfma_f32_16x16x32_bf16(afv, bfv, acc[m], 0, 0, 0);
            }
          }
        }
        const int hk0 = (kq == 0) ? 0 : kq * 288 - 128;
        const int nh = (kq == 0) ? 5 : 9;
#pragma unroll 3
        for (int s = 0; s < nh; s++) {
          int hk = hk0 + s * 32;
          bf16x8 bfv = ld8(w2 + hk);
          const bf16* ap = hA + hk + q * 8;
#pragma unroll
          for (int m = 0; m < 4; m++) {
            bf16x8 afv = ld8(ap + (size_t)(m * 16 + lrow) * HD);
            acc[m] = __builtin_amdgcn_mfma_f32_16x16x32_bf16(afv, bfv, acc[m], 0, 0, 0);
          }
        }
      } else {
        // K-chain 2048 = hA@WB1 (0..1023) + hB@WB2 (1024..2047); quarter = 512
        const bf16* hB = p.bufB + (((t - 1) & 1) ? (size_t)BD * HD : 0);
        const bf16* hp = (kq < 2) ? hA : hB;
        const bf16* wp = (kq < 2) ? w1 : w2;
        const int k0 = (kq & 1) * 512;
#pragma unroll 4
        for (int s = 0; s < 16; s++) {
          int hk = k0 + s * 32;
          bf16x8 bfv = ld8(wp + hk);
          const bf16* ap = hp + hk + q * 8;
#pragma unroll
          for (int m = 0; m < 4; m++) {
            bf16x8 afv = ld8(ap + (size_t)(m * 16 + lrow) * HD);
            acc[m] = __builtin_amdgcn_mfma_f32_16x16x32_bf16(afv, bfv, acc[m], 0, 0, 0);
          }
        }
      }
      // D layout: col(N)=lane&15, row(M)=q*4+r  [m89-verified]
#pragma unroll
      for (int m = 0; m < 4; m++)
#pragma unroll
        for (int r = 0; r < 4; r++)
          part[wv][lrow][m * 16 + q * 4 + r] = acc[m][r];
    }
    __syncthreads();

    const bool ew = (ecs == 0) ? (t < TD) : (t >= 1);
    if (ew) {
      const int wb = ecs * 4;
      float g4[4];
#pragma unroll
      for (int g = 0; g < 4; g++) {
        int n = g * 4 + ejj;
        g4[g] = ebias[g] + part[wb + 0][n][eb] + part[wb + 1][n][eb] +
                part[wb + 2][n][eb] + part[wb + 3][n][eb];
      }
      float cold = ec[eidx];
      float cn = sigf(g4[1]) * cold + sigf(g4[0]) * tanhf(g4[2]);
      float hn = sigf(g4[3]) * tanhf(cn);
      ec[eidx] = cn;
      if (ecs == 0) {
        p.bufA[(((t + 1) & 1) ? (size_t)BD * HD : 0) + eidx] = (bf16)hn;
      } else {
        p.bufB[((t & 1) ? (size_t)BD * HD : 0) + eidx] = (bf16)hn;
        p.outs[((size_t)(t - 1) * BD + eb) * HD + ej] = (bf16)hn;
      }
    }
    if (t < TD) grid_barrier(p.bar, t + 1);
  }
}

// out[T*B, V] = outs[T*B, H] @ Wfc[V, H]^T + bfc.  OUTPUT FP32.
__global__ void fc_k(const bf16* outs, const bf16* Wfc, const float* bfc, float* out) {
  const int tid = threadIdx.x;
  const int wv = tid >> 6, lane = tid & 63;
  const int lrow = lane & 15, q = lane >> 4;
  const int row0 = blockIdx.x * 64 + wv * 16;
  const bf16* arow = outs + (size_t)(row0 + lrow) * HD + q * 8;
  const bf16* wrow[8];
#pragma unroll
  for (int ct = 0; ct < 8; ct++) wrow[ct] = Wfc + (size_t)(ct * 16 + lrow) * HD + q * 8;
  f32x4 acc[8] = {};
#pragma unroll 2
  for (int s = 0; s < 32; s++) {
    bf16x8 afv = ld8(arow + s * 32);
#pragma unroll
    for (int ct = 0; ct < 8; ct++) {
      bf16x8 bfv = ld8(wrow[ct] + s * 32);
      acc[ct] = __builtin_amdgcn_mfma_f32_16x16x32_bf16(afv, bfv, acc[ct], 0, 0, 0);
    }
  }
#pragma unroll
  for (int ct = 0; ct < 8; ct++) {
    float bv = bfc[ct * 16 + lrow];
#pragma unroll
    for (int r = 0; r < 4; r++)
      out[(size_t)(row0 + q * 4 + r) * VD + ct * 16 + lrow] = acc[ct][r] + bv;
  }
}

// final states: (hA, cA, hB, cB) appended after out[T*B,V], FP32.
__global__ void tail_k(const char* ws, float* out) {
  int i = blockIdx.x * 256 + threadIdx.x;  // 65536
  float* o = out + (size_t)TD * BD * VD;
  o[i]             = (float)((const bf16*)(ws + OFF_BUFA))[i];  // hA final: parity 0
  o[65536 + i]     = ((const float*)(ws + OFF_CAF))[i];
  o[2 * 65536 + i] = (float)((const bf16*)(ws + OFF_BUFB))[i];  // hB final: parity 0
  o[3 * 65536 + i] = ((const float*)(ws + OFF_CBF))[i];
}

extern "C" void kernel_launch(void* const* d_in, const int* in_sizes, int n_in,
                              void* d_out, int out_size, void* d_ws, size_t ws_size,
                              hipStream_t stream) {
  const float* x   = (const float*)d_in[0];
  const float* hA  = (const float*)d_in[1];
  const float* cA  = (const float*)d_in[2];
  const float* hB  = (const float*)d_in[3];
  const float* cB  = (const float*)d_in[4];
  const float* WA1 = (const float*)d_in[5];
  const float* bA1 = (const float*)d_in[6];
  const float* WA2 = (const float*)d_in[7];
  const float* bA2 = (const float*)d_in[8];
  const float* WB1 = (const float*)d_in[9];
  const float* bB1 = (const float*)d_in[10];
  const float* WB2 = (const float*)d_in[11];
  const float* bB2 = (const float*)d_in[12];
  const float* Wfc = (const float*)d_in[13];
  const float* bfc = (const float*)d_in[14];

  char* ws = (char*)d_ws;

  conv_k<<<(15335424 / 4 + 255) / 256, 256, 0, stream>>>(x, WA1, WA2, WB1, WB2, Wfc, ws);
  init_k<<<256, 256, 0, stream>>>(hA, cA, hB, cB, ws);

  Params p{(const bf16*)(ws + OFF_XW), (const bf16*)(ws + OFF_WA1),
           (const bf16*)(ws + OFF_WA2), (const bf16*)(ws + OFF_WB1),
           (const bf16*)(ws + OFF_WB2),
           bA1, bA2, bB1, bB2,
           (bf16*)(ws + OFF_BUFA), (bf16*)(ws + OFF_BUFB), (bf16*)(ws + OFF_OUTS),
           (float*)(ws + OFF_CAF), (float*)(ws + OFF_CBF),
           (int*)(ws + OFF_BAR)};
  void* args[] = {&p};
  if (hipLaunchCooperativeKernel(lstm_k, dim3(NB), dim3(512), args, 0, stream) != hipSuccess) {
    // fallback: 256 blocks x 512 thr, 33 KB LDS -> 1 block/CU co-resident
    lstm_k<<<NB, 512, 0, stream>>>(p);
  }

  fc_k<<<256, 256, 0, stream>>>((const bf16*)(ws + OFF_OUTS), (const bf16*)(ws + OFF_WFC),
                                bfc, (float*)d_out);
  tail_k<<<256, 256, 0, stream>>>(ws, (float*)d_out);
}

// Round 7
// 12958.380 us; speedup vs baseline: 2.8710x; 2.8710x over previous
//
#include <hip/hip_runtime.h>

#define VD 128
#define HD 1024
#define BD 64
#define TD 256
#define NB 256  // persistent grid: 1 block/CU

typedef __bf16 bf16;
typedef __bf16 bf16x8 __attribute__((ext_vector_type(8)));
typedef __bf16 bf16x4 __attribute__((ext_vector_type(4)));
typedef float f32x4 __attribute__((ext_vector_type(4)));

// ---- ws layout (byte offsets) ----
#define OFF_OUTS 0ull                           // bf16 [T][B][H]   33,554,432 B
#define OFF_XW   33554432ull                    // bf16 [T][B][V]    4,194,304 B
#define OFF_WA1  (OFF_XW  + 4194304ull)         // bf16 [4H][V]      1,048,576 B
#define OFF_WA2  (OFF_WA1 + 1048576ull)         // bf16 [4H][H]      8,388,608 B
#define OFF_WB1  (OFF_WA2 + 8388608ull)         // bf16 [4H][H]
#define OFF_WB2  (OFF_WB1 + 8388608ull)         // bf16 [4H][H]
#define OFF_WFC  (OFF_WB2 + 8388608ull)         // bf16 [V][H]         262,144 B
#define OFF_BUFA (OFF_WFC + 262144ull)          // bf16 [2][B][H]      262,144 B
#define OFF_BUFB (OFF_BUFA + 262144ull)
#define OFF_CAF  (OFF_BUFB + 262144ull)         // fp32 [B][H]
#define OFF_CBF  (OFF_CAF + 262144ull)
#define OFF_BAR  (OFF_CBF + 262144ull)          // int[2]

struct Params {
  const bf16 *x, *WA1, *WA2, *WB1, *WB2;  // bf16 canonical (ws)
  const float *bA1, *bA2, *bB1, *bB2;     // fp32 biases (inputs)
  bf16 *bufA, *bufB, *outs;
  float *cA, *cB;
  int *bar;
};

__device__ __forceinline__ bf16x8 ld8(const bf16* p) {
  return *reinterpret_cast<const bf16x8*>(p);
}
__device__ __forceinline__ float sigf(float x) { return 1.f / (1.f + __expf(-x)); }

// Cross-XCD sense barrier, v2. R6 lesson: ACQUIRE on every poll = per-poll L2
// invalidate by 256 spinners -> destroys XCD-resident weight cache while
// stragglers compute (144 us/phase, 3.5 MB/phase HBM refetch). Fix:
//   - polls are RELAXED (coherent read, no cache maintenance)
//   - arrival / sense-bump are RELEASE RMWs (ordering, no invalidate)
//   - exactly ONE __threadfence per block per side, thread 0 only.
// __syncthreads' implied per-wave vmcnt(0) puts all waves' stores in L2
// before thread 0's release fence flushes them.
__device__ __forceinline__ void grid_barrier(int* bar, int target) {
  __syncthreads();
  if (threadIdx.x == 0) {
    __threadfence();  // release: write back our h/c so other XCDs see them
    if (__hip_atomic_fetch_add(&bar[0], 1, __ATOMIC_RELEASE, __HIP_MEMORY_SCOPE_AGENT) == NB - 1) {
      __hip_atomic_store(&bar[0], 0, __ATOMIC_RELAXED, __HIP_MEMORY_SCOPE_AGENT);
      __hip_atomic_fetch_add(&bar[1], 1, __ATOMIC_RELEASE, __HIP_MEMORY_SCOPE_AGENT);
    } else {
      while (__hip_atomic_load(&bar[1], __ATOMIC_RELAXED, __HIP_MEMORY_SCOPE_AGENT) < target) {
        __builtin_amdgcn_s_sleep(4);
      }
    }
    __threadfence();  // acquire: invalidate stale lines before reading remote h
  }
  __syncthreads();
}

// fp32 -> bf16 staging: x, WA1, WA2, WB1, WB2, Wfc. 4 elems/thread via float4.
__global__ void conv_k(const float* x, const float* WA1, const float* WA2,
                       const float* WB1, const float* WB2, const float* Wfc,
                       char* ws) {
  const size_t g4 = (size_t)blockIdx.x * 256 + threadIdx.x;
  size_t i = g4 * 4;
  const float* src;
  bf16* dst;
  size_t off;
  if (i < 2097152ull)        { src = x;   dst = (bf16*)(ws + OFF_XW);  off = i; }
  else if (i < 2621440ull)   { src = WA1; dst = (bf16*)(ws + OFF_WA1); off = i - 2097152ull; }
  else if (i < 6815744ull)   { src = WA2; dst = (bf16*)(ws + OFF_WA2); off = i - 2621440ull; }
  else if (i < 11010048ull)  { src = WB1; dst = (bf16*)(ws + OFF_WB1); off = i - 6815744ull; }
  else if (i < 15204352ull)  { src = WB2; dst = (bf16*)(ws + OFF_WB2); off = i - 11010048ull; }
  else if (i < 15335424ull)  { src = Wfc; dst = (bf16*)(ws + OFF_WFC); off = i - 15204352ull; }
  else return;
  float4 v = *reinterpret_cast<const float4*>(src + off);
  bf16x4 o = { (bf16)v.x, (bf16)v.y, (bf16)v.z, (bf16)v.w };
  *reinterpret_cast<bf16x4*>(dst + off) = o;
}

__global__ void init_k(const float* hA, const float* cA, const float* hB, const float* cB,
                       char* ws) {
  int i = blockIdx.x * 256 + threadIdx.x;  // 65536 = B*H
  ((bf16*)(ws + OFF_BUFA))[i] = (bf16)hA[i];
  ((bf16*)(ws + OFF_BUFB))[i] = (bf16)hB[i];
  ((float*)(ws + OFF_CAF))[i] = cA[i];
  ((float*)(ws + OFF_CBF))[i] = cB[i];
  if (i == 0) { ((int*)(ws + OFF_BAR))[0] = 0; ((int*)(ws + OFF_BAR))[1] = 0; }
}

// Persistent fused 2-layer LSTM: 257 phases, grid barrier between phases.
// Phase t: A-step t (t<T) + B-step t-1 (t>=1). Block bk owns h-columns
// j0..j0+3 of BOTH cells. Waves: wv>>2 = cell, wv&3 = K-quarter.
// mfma_f32_16x16x32_bf16 -> LDS partials -> 512-thread elementwise update.
__global__ void __launch_bounds__(512) lstm_k(Params p) {
  __shared__ float part[8][16][65];
  const int tid = threadIdx.x;
  const int wv = tid >> 6, lane = tid & 63;
  const int lrow = lane & 15, q = lane >> 4;
  const int j0 = blockIdx.x * 4;
  const int cs = wv >> 2, kq = wv & 3;
  const int gate = lrow >> 2, jj = lrow & 3;
  const int grow = gate * HD + j0 + jj;

  const bf16 *w1, *w2;
  if (cs == 0) { w1 = p.WA1 + grow * VD + q * 8; w2 = p.WA2 + (size_t)grow * HD + q * 8; }
  else         { w1 = p.WB1 + (size_t)grow * HD + q * 8; w2 = p.WB2 + (size_t)grow * HD + q * 8; }

  // elementwise role: tid 0..255 -> cell A, 256..511 -> cell B; (batch, jj)
  const int eb = tid & 63;
  const int ejj = (tid >> 6) & 3;
  const int ecs = tid >> 8;
  const int ej = j0 + ejj;
  const int eidx = eb * HD + ej;
  float ebias[4];
  {
    const float* b1 = ecs ? p.bB1 : p.bA1;
    const float* b2 = ecs ? p.bB2 : p.bA2;
#pragma unroll
    for (int g = 0; g < 4; g++) ebias[g] = b1[g * HD + ej] + b2[g * HD + ej];
  }
  float* ec = ecs ? p.cB : p.cA;

#pragma unroll 1
  for (int t = 0; t <= TD; t++) {
    const bool active = (cs == 0) ? (t < TD) : (t >= 1);
    const bf16* hA = p.bufA + ((t & 1) ? (size_t)BD * HD : 0);
    if (active) {
      f32x4 acc[4] = {};
      if (cs == 0) {
        // K-chain 1152 = x(128) + hA(1024); quarter kq = [kq*288, kq*288+288)
        if (kq == 0) {
          const bf16* xb = p.x + (size_t)t * BD * VD + q * 8;
#pragma unroll
          for (int s = 0; s < 4; s++) {
            bf16x8 bfv = ld8(w1 + s * 32);
            const bf16* ap = xb + s * 32;
#pragma unroll
            for (int m = 0; m < 4; m++) {
              bf16x8 afv = ld8(ap + (m * 16 + lrow) * VD);
              acc[m] = __builtin_amdgcn_mfma_f32_16x16x32_bf16(afv, bfv, acc[m], 0, 0, 0);
            }
          }
        }
        const int hk0 = (kq == 0) ? 0 : kq * 288 - 128;
        const int nh = (kq == 0) ? 5 : 9;
#pragma unroll 3
        for (int s = 0; s < nh; s++) {
          int hk = hk0 + s * 32;
          bf16x8 bfv = ld8(w2 + hk);
          const bf16* ap = hA + hk + q * 8;
#pragma unroll
          for (int m = 0; m < 4; m++) {
            bf16x8 afv = ld8(ap + (size_t)(m * 16 + lrow) * HD);
            acc[m] = __builtin_amdgcn_mfma_f32_16x16x32_bf16(afv, bfv, acc[m], 0, 0, 0);
          }
        }
      } else {
        // K-chain 2048 = hA@WB1 (0..1023) + hB@WB2 (1024..2047); quarter = 512
        const bf16* hB = p.bufB + (((t - 1) & 1) ? (size_t)BD * HD : 0);
        const bf16* hp = (kq < 2) ? hA : hB;
        const bf16* wp = (kq < 2) ? w1 : w2;
        const int k0 = (kq & 1) * 512;
#pragma unroll 4
        for (int s = 0; s < 16; s++) {
          int hk = k0 + s * 32;
          bf16x8 bfv = ld8(wp + hk);
          const bf16* ap = hp + hk + q * 8;
#pragma unroll
          for (int m = 0; m < 4; m++) {
            bf16x8 afv = ld8(ap + (size_t)(m * 16 + lrow) * HD);
            acc[m] = __builtin_amdgcn_mfma_f32_16x16x32_bf16(afv, bfv, acc[m], 0, 0, 0);
          }
        }
      }
      // D layout: col(N)=lane&15, row(M)=q*4+r  [m89-verified]
#pragma unroll
      for (int m = 0; m < 4; m++)
#pragma unroll
        for (int r = 0; r < 4; r++)
          part[wv][lrow][m * 16 + q * 4 + r] = acc[m][r];
    }
    __syncthreads();

    const bool ew = (ecs == 0) ? (t < TD) : (t >= 1);
    if (ew) {
      const int wb = ecs * 4;
      float g4[4];
#pragma unroll
      for (int g = 0; g < 4; g++) {
        int n = g * 4 + ejj;
        g4[g] = ebias[g] + part[wb + 0][n][eb] + part[wb + 1][n][eb] +
                part[wb + 2][n][eb] + part[wb + 3][n][eb];
      }
      float cold = ec[eidx];
      float cn = sigf(g4[1]) * cold + sigf(g4[0]) * tanhf(g4[2]);
      float hn = sigf(g4[3]) * tanhf(cn);
      ec[eidx] = cn;
      if (ecs == 0) {
        p.bufA[(((t + 1) & 1) ? (size_t)BD * HD : 0) + eidx] = (bf16)hn;
      } else {
        p.bufB[((t & 1) ? (size_t)BD * HD : 0) + eidx] = (bf16)hn;
        p.outs[((size_t)(t - 1) * BD + eb) * HD + ej] = (bf16)hn;
      }
    }
    if (t < TD) grid_barrier(p.bar, t + 1);
  }
}

// out[T*B, V] = outs[T*B, H] @ Wfc[V, H]^T + bfc.  OUTPUT FP32.
__global__ void fc_k(const bf16* outs, const bf16* Wfc, const float* bfc, float* out) {
  const int tid = threadIdx.x;
  const int wv = tid >> 6, lane = tid & 63;
  const int lrow = lane & 15, q = lane >> 4;
  const int row0 = blockIdx.x * 64 + wv * 16;
  const bf16* arow = outs + (size_t)(row0 + lrow) * HD + q * 8;
  const bf16* wrow[8];
#pragma unroll
  for (int ct = 0; ct < 8; ct++) wrow[ct] = Wfc + (size_t)(ct * 16 + lrow) * HD + q * 8;
  f32x4 acc[8] = {};
#pragma unroll 2
  for (int s = 0; s < 32; s++) {
    bf16x8 afv = ld8(arow + s * 32);
#pragma unroll
    for (int ct = 0; ct < 8; ct++) {
      bf16x8 bfv = ld8(wrow[ct] + s * 32);
      acc[ct] = __builtin_amdgcn_mfma_f32_16x16x32_bf16(afv, bfv, acc[ct], 0, 0, 0);
    }
  }
#pragma unroll
  for (int ct = 0; ct < 8; ct++) {
    float bv = bfc[ct * 16 + lrow];
#pragma unroll
    for (int r = 0; r < 4; r++)
      out[(size_t)(row0 + q * 4 + r) * VD + ct * 16 + lrow] = acc[ct][r] + bv;
  }
}

// final states: (hA, cA, hB, cB) appended after out[T*B,V], FP32.
__global__ void tail_k(const char* ws, float* out) {
  int i = blockIdx.x * 256 + threadIdx.x;  // 65536
  float* o = out + (size_t)TD * BD * VD;
  o[i]             = (float)((const bf16*)(ws + OFF_BUFA))[i];  // hA final: parity 0
  o[65536 + i]     = ((const float*)(ws + OFF_CAF))[i];
  o[2 * 65536 + i] = (float)((const bf16*)(ws + OFF_BUFB))[i];  // hB final: parity 0
  o[3 * 65536 + i] = ((const float*)(ws + OFF_CBF))[i];
}

extern "C" void kernel_launch(void* const* d_in, const int* in_sizes, int n_in,
                              void* d_out, int out_size, void* d_ws, size_t ws_size,
                              hipStream_t stream) {
  const float* x   = (const float*)d_in[0];
  const float* hA  = (const float*)d_in[1];
  const float* cA  = (const float*)d_in[2];
  const float* hB  = (const float*)d_in[3];
  const float* cB  = (const float*)d_in[4];
  const float* WA1 = (const float*)d_in[5];
  const float* bA1 = (const float*)d_in[6];
  const float* WA2 = (const float*)d_in[7];
  const float* bA2 = (const float*)d_in[8];
  const float* WB1 = (const float*)d_in[9];
  const float* bB1 = (const float*)d_in[10];
  const float* WB2 = (const float*)d_in[11];
  const float* bB2 = (const float*)d_in[12];
  const float* Wfc = (const float*)d_in[13];
  const float* bfc = (const float*)d_in[14];

  char* ws = (char*)d_ws;

  conv_k<<<(15335424 / 4 + 255) / 256, 256, 0, stream>>>(x, WA1, WA2, WB1, WB2, Wfc, ws);
  init_k<<<256, 256, 0, stream>>>(hA, cA, hB, cB, ws);

  Params p{(const bf16*)(ws + OFF_XW), (const bf16*)(ws + OFF_WA1),
           (const bf16*)(ws + OFF_WA2), (const bf16*)(ws + OFF_WB1),
           (const bf16*)(ws + OFF_WB2),
           bA1, bA2, bB1, bB2,
           (bf16*)(ws + OFF_BUFA), (bf16*)(ws + OFF_BUFB), (bf16*)(ws + OFF_OUTS),
           (float*)(ws + OFF_CAF), (float*)(ws + OFF_CBF),
           (int*)(ws + OFF_BAR)};
  void* args[] = {&p};
  if (hipLaunchCooperativeKernel(lstm_k, dim3(NB), dim3(512), args, 0, stream) != hipSuccess) {
    // fallback: 256 blocks x 512 thr, 33 KB LDS -> 1 block/CU co-resident
    lstm_k<<<NB, 512, 0, stream>>>(p);
  }

  fc_k<<<256, 256, 0, stream>>>((const bf16*)(ws + OFF_OUTS), (const bf16*)(ws + OFF_WFC),
                                bfc, (float*)d_out);
  tail_k<<<256, 256, 0, stream>>>(ws, (float*)d_out);
}

// Round 9
// 5359.674 us; speedup vs baseline: 6.9413x; 2.4178x over previous
//
#include <hip/hip_runtime.h>

#define VD 128
#define HD 1024
#define BD 64
#define TD 256
#define NB 256  // persistent grid: 1 block/CU

typedef __bf16 bf16;
typedef __bf16 bf16x8 __attribute__((ext_vector_type(8)));
typedef __bf16 bf16x4 __attribute__((ext_vector_type(4)));
typedef float f32x4 __attribute__((ext_vector_type(4)));
typedef unsigned int u32;

// ---- ws layout (byte offsets) ----
#define OFF_OUTS 0ull                           // bf16 [T][B][H]   33,554,432 B
#define OFF_XW   33554432ull                    // bf16 [T][B][V]    4,194,304 B
#define OFF_WA1  (OFF_XW  + 4194304ull)         // bf16 [4H][V]      1,048,576 B
#define OFF_WA2  (OFF_WA1 + 1048576ull)         // bf16 [4H][H]      8,388,608 B
#define OFF_WB1  (OFF_WA2 + 8388608ull)         // bf16 [4H][H]
#define OFF_WB2  (OFF_WB1 + 8388608ull)         // bf16 [4H][H]
#define OFF_WFC  (OFF_WB2 + 8388608ull)         // bf16 [V][H]         262,144 B
#define OFF_BUFA (OFF_WFC + 262144ull)          // u32  [2][B][H/2]    262,144 B
#define OFF_BUFB (OFF_BUFA + 262144ull)         // u32  [2][B][H/2]
#define OFF_BAR  (OFF_BUFB + 262144ull)         // int[2]

struct Params {
  const bf16 *x, *WA1, *WA2, *WB1, *WB2;  // bf16 canonical (ws), stays L2-resident
  const float *bA1, *bA2, *bB1, *bB2;     // fp32 biases (inputs)
  const float *hA_in, *cA_in, *hB_in, *cB_in;
  u32 *bufA4, *bufB4;                     // h double-buffers, dword-packed bf16x2
  u32 *outs4;                             // outs history, dword-packed
  float *out;                             // d_out (fp32)
  int *bar;
};

__device__ __forceinline__ bf16x8 ld8(const bf16* p) {
  return *reinterpret_cast<const bf16x8*>(p);
}
__device__ __forceinline__ float sigf(float x) { return 1.f / (1.f + __expf(-x)); }

__device__ __forceinline__ int aadd(int* p, int v) {
  return __hip_atomic_fetch_add(p, v, __ATOMIC_RELAXED, __HIP_MEMORY_SCOPE_AGENT);
}
__device__ __forceinline__ int ald(const int* p) {
  return __hip_atomic_load((int*)p, __ATOMIC_RELAXED, __HIP_MEMORY_SCOPE_AGENT);
}
__device__ __forceinline__ void ast32(u32* p, u32 v) {
  __hip_atomic_store(p, v, __ATOMIC_RELAXED, __HIP_MEMORY_SCOPE_AGENT);
}

// Four 16B system-scope loads (sc0 sc1: bypass stale per-XCD L2, read coherence
// point, coalesce like normal loads). One vmcnt(0) per batch of 4 — 16x fewer
// transactions than R8's per-dword atomics. "=&v": early-clobber so dest quads
// don't alias the address pairs.
__device__ __forceinline__ void ldh8x4(const u32* p, bf16x8& f0, bf16x8& f1,
                                       bf16x8& f2, bf16x8& f3) {
  const u32* p1 = p + 16 * 512;
  const u32* p2 = p + 32 * 512;
  const u32* p3 = p + 48 * 512;
  asm volatile(
      "global_load_dwordx4 %0, %4, off sc0 sc1\n\t"
      "global_load_dwordx4 %1, %5, off sc0 sc1\n\t"
      "global_load_dwordx4 %2, %6, off sc0 sc1\n\t"
      "global_load_dwordx4 %3, %7, off sc0 sc1\n\t"
      "s_waitcnt vmcnt(0)"
      : "=&v"(f0), "=&v"(f1), "=&v"(f2), "=&v"(f3)
      : "v"(p), "v"(p1), "v"(p2), "v"(p3)
      : "memory");
}

// Barrier v4: single-level, all-RMW, monotonic (no resets), ZERO cache
// maintenance. Spin = relaxed agent atomic LOAD (coherence-point read, no
// line ownership thrash). Visibility: producers' write-through atomic h
// stores are vmcnt-drained at __syncthreads before the arrival RMW;
// consumers read h via sc0sc1 loads. No fences anywhere in the kernel.
__device__ __forceinline__ void grid_barrier(int* bar, int target) {
  __syncthreads();
  if (threadIdx.x == 0) {
    if (aadd(&bar[0], 1) == target * NB - 1) {
      aadd(&bar[1], 1);  // last arrival releases
    } else {
      while (ald(&bar[1]) < target) __builtin_amdgcn_s_sleep(8);
    }
  }
  __syncthreads();
}

// fp32 -> bf16 staging: x, WA1, WA2, WB1, WB2, Wfc; + zero barrier counters.
__global__ void conv_k(const float* x, const float* WA1, const float* WA2,
                       const float* WB1, const float* WB2, const float* Wfc,
                       char* ws) {
  if (blockIdx.x == 0 && threadIdx.x < 2) ((int*)(ws + OFF_BAR))[threadIdx.x] = 0;
  const size_t g4 = (size_t)blockIdx.x * 256 + threadIdx.x;
  size_t i = g4 * 4;
  const float* src;
  bf16* dst;
  size_t off;
  if (i < 2097152ull)        { src = x;   dst = (bf16*)(ws + OFF_XW);  off = i; }
  else if (i < 2621440ull)   { src = WA1; dst = (bf16*)(ws + OFF_WA1); off = i - 2097152ull; }
  else if (i < 6815744ull)   { src = WA2; dst = (bf16*)(ws + OFF_WA2); off = i - 2621440ull; }
  else if (i < 11010048ull)  { src = WB1; dst = (bf16*)(ws + OFF_WB1); off = i - 6815744ull; }
  else if (i < 15204352ull)  { src = WB2; dst = (bf16*)(ws + OFF_WB2); off = i - 11010048ull; }
  else if (i < 15335424ull)  { src = Wfc; dst = (bf16*)(ws + OFF_WFC); off = i - 15204352ull; }
  else return;
  float4 v = *reinterpret_cast<const float4*>(src + off);
  bf16x4 o = { (bf16)v.x, (bf16)v.y, (bf16)v.z, (bf16)v.w };
  *reinterpret_cast<bf16x4*>(dst + off) = o;
}

// Persistent fused 2-layer LSTM. Phase t: A-step t (t<T) + B-step t-1 (t>=1).
// Block bk owns h-columns j0..j0+3 of BOTH cells. MFMA waves: wv>>2 = cell,
// wv&3 = K-quarter (math core identical to R5/R7; h via sc0sc1 16B loads).
// Elementwise: tid<256, thread = (cell, batch, column-pair); c in REGISTERS.
__global__ void __launch_bounds__(512) lstm_k(Params p) {
  __shared__ float part[8][16][65];
  const int tid = threadIdx.x;
  const int wv = tid >> 6, lane = tid & 63;
  const int lrow = lane & 15, q = lane >> 4;
  const int j0 = blockIdx.x * 4;
  const int cs = wv >> 2, kq = wv & 3;
  const int gate = lrow >> 2, jj = lrow & 3;
  const int grow = gate * HD + j0 + jj;

  const bf16 *w1, *w2;
  if (cs == 0) { w1 = p.WA1 + grow * VD + q * 8; w2 = p.WA2 + (size_t)grow * HD + q * 8; }
  else         { w1 = p.WB1 + (size_t)grow * HD + q * 8; w2 = p.WB2 + (size_t)grow * HD + q * 8; }

  // elementwise role (tid<256): ecs=cell, eb=batch, jp=column pair
  const int ecs = tid >> 7;
  const int eb = (tid & 127) >> 1;
  const int jp = tid & 1;
  const int ej0 = j0 + jp * 2;
  const int edw = eb * 512 + (j0 >> 1) + jp;  // dword index in [B][H/2]
  float ebias[2][4], creg[2], hfin[2];
  if (tid < 256) {
    const float* b1 = ecs ? p.bB1 : p.bA1;
    const float* b2 = ecs ? p.bB2 : p.bA2;
    const float* ci = ecs ? p.cB_in : p.cA_in;
    const float* hi = ecs ? p.hB_in : p.hA_in;
#pragma unroll
    for (int s = 0; s < 2; s++) {
      creg[s] = ci[eb * HD + ej0 + s];
      hfin[s] = 0.f;
#pragma unroll
      for (int g = 0; g < 4; g++) ebias[s][g] = b1[g * HD + ej0 + s] + b2[g * HD + ej0 + s];
    }
    bf16 h0 = (bf16)hi[eb * HD + ej0], h1 = (bf16)hi[eb * HD + ej0 + 1];
    u32 pk = (u32)__builtin_bit_cast(unsigned short, h0) |
             ((u32)__builtin_bit_cast(unsigned short, h1) << 16);
    ast32((ecs ? p.bufB4 : p.bufA4) + edw, pk);  // initial h, parity 0
  }
  grid_barrier(p.bar, 1);

#pragma unroll 1
  for (int t = 0; t <= TD; t++) {
    const bool active = (cs == 0) ? (t < TD) : (t >= 1);
    const u32* hA4 = p.bufA4 + ((t & 1) ? BD * 512 : 0);
    if (active) {
      f32x4 acc[4] = {};
      if (cs == 0) {
        // K-chain 1152 = x(128, L2-cached) + hA(1024, coherent); kq = [kq*288,+288)
        if (kq == 0) {
          const bf16* xb = p.x + (size_t)t * BD * VD + q * 8;
#pragma unroll
          for (int s = 0; s < 4; s++) {
            bf16x8 bfv = ld8(w1 + s * 32);
            const bf16* ap = xb + s * 32;
#pragma unroll
            for (int m = 0; m < 4; m++) {
              bf16x8 afv = ld8(ap + (m * 16 + lrow) * VD);
              acc[m] = __builtin_amdgcn_mfma_f32_16x16x32_bf16(afv, bfv, acc[m], 0, 0, 0);
            }
          }
        }
        const int hk0 = (kq == 0) ? 0 : kq * 288 - 128;
        const int nh = (kq == 0) ? 5 : 9;
#pragma unroll 1
        for (int s = 0; s < nh; s++) {
          int hk = hk0 + s * 32;
          bf16x8 bfv = ld8(w2 + hk);
          const u32* ap = hA4 + ((hk + q * 8) >> 1) + lrow * 512;
          bf16x8 a0, a1, a2, a3;
          ldh8x4(ap, a0, a1, a2, a3);
          acc[0] = __builtin_amdgcn_mfma_f32_16x16x32_bf16(a0, bfv, acc[0], 0, 0, 0);
          acc[1] = __builtin_amdgcn_mfma_f32_16x16x32_bf16(a1, bfv, acc[1], 0, 0, 0);
          acc[2] = __builtin_amdgcn_mfma_f32_16x16x32_bf16(a2, bfv, acc[2], 0, 0, 0);
          acc[3] = __builtin_amdgcn_mfma_f32_16x16x32_bf16(a3, bfv, acc[3], 0, 0, 0);
        }
      } else {
        // K-chain 2048 = hA@WB1 (0..1023) + hB@WB2 (1024..2047); quarter = 512
        const u32* hB4 = p.bufB4 + (((t - 1) & 1) ? BD * 512 : 0);
        const u32* hp4 = (kq < 2) ? hA4 : hB4;
        const bf16* wp = (kq < 2) ? w1 : w2;
        const int k0 = (kq & 1) * 512;
#pragma unroll 1
        for (int s = 0; s < 16; s++) {
          int hk = k0 + s * 32;
          bf16x8 bfv = ld8(wp + hk);
          const u32* ap = hp4 + ((hk + q * 8) >> 1) + lrow * 512;
          bf16x8 a0, a1, a2, a3;
          ldh8x4(ap, a0, a1, a2, a3);
          acc[0] = __builtin_amdgcn_mfma_f32_16x16x32_bf16(a0, bfv, acc[0], 0, 0, 0);
          acc[1] = __builtin_amdgcn_mfma_f32_16x16x32_bf16(a1, bfv, acc[1], 0, 0, 0);
          acc[2] = __builtin_amdgcn_mfma_f32_16x16x32_bf16(a2, bfv, acc[2], 0, 0, 0);
          acc[3] = __builtin_amdgcn_mfma_f32_16x16x32_bf16(a3, bfv, acc[3], 0, 0, 0);
        }
      }
      // D layout: col(N)=lane&15, row(M)=q*4+r  [m89-verified]
#pragma unroll
      for (int m = 0; m < 4; m++)
#pragma unroll
        for (int r = 0; r < 4; r++)
          part[wv][lrow][m * 16 + q * 4 + r] = acc[m][r];
    }
    __syncthreads();

    if (tid < 256) {
      const bool ew = (ecs == 0) ? (t < TD) : (t >= 1);
      if (ew) {
        const int wb = ecs * 4;
        u32 pk = 0;
#pragma unroll
        for (int s = 0; s < 2; s++) {
          const int cjj = jp * 2 + s;
          float g4[4];
#pragma unroll
          for (int g = 0; g < 4; g++) {
            int n = g * 4 + cjj;
            g4[g] = ebias[s][g] + part[wb + 0][n][eb] + part[wb + 1][n][eb] +
                    part[wb + 2][n][eb] + part[wb + 3][n][eb];
          }
          float cn = sigf(g4[1]) * creg[s] + sigf(g4[0]) * tanhf(g4[2]);
          creg[s] = cn;
          float hn = sigf(g4[3]) * tanhf(cn);
          hfin[s] = hn;
          pk |= (u32)__builtin_bit_cast(unsigned short, (bf16)hn) << (16 * s);
        }
        if (ecs == 0) {
          ast32(p.bufA4 + (((t + 1) & 1) ? BD * 512 : 0) + edw, pk);
        } else {
          ast32(p.bufB4 + ((t & 1) ? BD * 512 : 0) + edw, pk);
          p.outs4[(size_t)(t - 1) * BD * 512 + edw] = pk;  // plain; kernel-end flush
        }
      }
    }
    if (t < TD) grid_barrier(p.bar, t + 2);
  }

  // final states straight from registers: [hA, cA, hB, cB] fp32 after out[T*B,V]
  if (tid < 256) {
    float* o = p.out + (size_t)TD * BD * VD + (size_t)ecs * 2 * 65536;
#pragma unroll
    for (int s = 0; s < 2; s++) {
      o[eb * HD + ej0 + s] = hfin[s];
      o[65536 + eb * HD + ej0 + s] = creg[s];
    }
  }
}

// out[T*B, V] = outs[T*B, H] @ Wfc[V, H]^T + bfc.  OUTPUT FP32.
__global__ void fc_k(const bf16* outs, const bf16* Wfc, const float* bfc, float* out) {
  const int tid = threadIdx.x;
  const int wv = tid >> 6, lane = tid & 63;
  const int lrow = lane & 15, q = lane >> 4;
  const int row0 = blockIdx.x * 64 + wv * 16;
  const bf16* arow = outs + (size_t)(row0 + lrow) * HD + q * 8;
  const bf16* wrow[8];
#pragma unroll
  for (int ct = 0; ct < 8; ct++) wrow[ct] = Wfc + (size_t)(ct * 16 + lrow) * HD + q * 8;
  f32x4 acc[8] = {};
#pragma unroll 2
  for (int s = 0; s < 32; s++) {
    bf16x8 afv = ld8(arow + s * 32);
#pragma unroll
    for (int ct = 0; ct < 8; ct++) {
      bf16x8 bfv = ld8(wrow[ct] + s * 32);
      acc[ct] = __builtin_amdgcn_mfma_f32_16x16x32_bf16(afv, bfv, acc[ct], 0, 0, 0);
    }
  }
#pragma unroll
  for (int ct = 0; ct < 8; ct++) {
    float bv = bfc[ct * 16 + lrow];
#pragma unroll
    for (int r = 0; r < 4; r++)
      out[(size_t)(row0 + q * 4 + r) * VD + ct * 16 + lrow] = acc[ct][r] + bv;
  }
}

extern "C" void kernel_launch(void* const* d_in, const int* in_sizes, int n_in,
                              void* d_out, int out_size, void* d_ws, size_t ws_size,
                              hipStream_t stream) {
  const float* x   = (const float*)d_in[0];
  const float* hA  = (const float*)d_in[1];
  const float* cA  = (const float*)d_in[2];
  const float* hB  = (const float*)d_in[3];
  const float* cB  = (const float*)d_in[4];
  const float* WA1 = (const float*)d_in[5];
  const float* bA1 = (const float*)d_in[6];
  const float* WA2 = (const float*)d_in[7];
  const float* bA2 = (const float*)d_in[8];
  const float* WB1 = (const float*)d_in[9];
  const float* bB1 = (const float*)d_in[10];
  const float* WB2 = (const float*)d_in[11];
  const float* bB2 = (const float*)d_in[12];
  const float* Wfc = (const float*)d_in[13];
  const float* bfc = (const float*)d_in[14];

  char* ws = (char*)d_ws;

  conv_k<<<(15335424 / 4 + 255) / 256, 256, 0, stream>>>(x, WA1, WA2, WB1, WB2, Wfc, ws);

  Params p{(const bf16*)(ws + OFF_XW), (const bf16*)(ws + OFF_WA1),
           (const bf16*)(ws + OFF_WA2), (const bf16*)(ws + OFF_WB1),
           (const bf16*)(ws + OFF_WB2),
           bA1, bA2, bB1, bB2,
           hA, cA, hB, cB,
           (u32*)(ws + OFF_BUFA), (u32*)(ws + OFF_BUFB), (u32*)(ws + OFF_OUTS),
           (float*)d_out,
           (int*)(ws + OFF_BAR)};
  void* args[] = {&p};
  if (hipLaunchCooperativeKernel(lstm_k, dim3(NB), dim3(512), args, 0, stream) != hipSuccess) {
    lstm_k<<<NB, 512, 0, stream>>>(p);
  }

  fc_k<<<256, 256, 0, stream>>>((const bf16*)(ws + OFF_OUTS), (const bf16*)(ws + OFF_WFC),
                                bfc, (float*)d_out);
}